// Round 5
// baseline (374.824 us; speedup 1.0000x reference)
//
#include <hip/hip_runtime.h>
#include <stdint.h>

#define HIDDEN 1024
#define INTER  4096
#define ROWS   8192
#define BM     32              // rows per gemm block
#define GTHR   1024            // 16 waves per gemm block
#define KSUP   512             // k per superstep (staged in LDS)
#define NSUP   (INTER / KSUP)  // 8 supersteps

typedef unsigned long long u64;
typedef int v4i __attribute__((ext_vector_type(4)));

// ---------------------------------------------------------------------------
// Pack kernel.
//  blocks [0, 8192):        hs row b -> abits[b][w], bit j of word w = sign
//                           bit of element w*64+j  (natural bit order).
//  blocks [8192, 8192+1024): W row h -> sign bytes w8[h][k] (+1 -> 0x01,
//                           -1 -> 0xFF) and wscale[h] = mean|W[h,:]|.
// ---------------------------------------------------------------------------
__device__ __forceinline__ unsigned sbyte(float x) { return x < 0.0f ? 0xFFu : 0x01u; }

__global__ __launch_bounds__(256)
void pack_kernel(const float* __restrict__ hs, const float* __restrict__ W,
                 u64* __restrict__ abits, unsigned char* __restrict__ w8,
                 float* __restrict__ wscale) {
    int lane = threadIdx.x & 63;
    int wave = threadIdx.x >> 6;
    int b = blockIdx.x;

    if (b < ROWS) {
        const float* row = hs + (size_t)b * INTER;
        u64* dst = abits + (size_t)b * 64;
        #pragma unroll
        for (int w = wave; w < 64; w += 4) {
            float x = row[w * 64 + lane];          // coalesced
            u64 m = __ballot(x < 0.0f);            // bit lane = sign
            if (lane == 0) dst[w] = m;
        }
    } else {
        int h = b - ROWS;
        int t = threadIdx.x;
        const float4* row4 = (const float4*)(W + (size_t)h * INTER);
        float4 v0 = row4[t * 4 + 0];
        float4 v1 = row4[t * 4 + 1];
        float4 v2 = row4[t * 4 + 2];
        float4 v3 = row4[t * 4 + 3];
        float asum = fabsf(v0.x) + fabsf(v0.y) + fabsf(v0.z) + fabsf(v0.w)
                   + fabsf(v1.x) + fabsf(v1.y) + fabsf(v1.z) + fabsf(v1.w)
                   + fabsf(v2.x) + fabsf(v2.y) + fabsf(v2.z) + fabsf(v2.w)
                   + fabsf(v3.x) + fabsf(v3.y) + fabsf(v3.z) + fabsf(v3.w);
        uint4 ub;
        ub.x = sbyte(v0.x) | (sbyte(v0.y) << 8) | (sbyte(v0.z) << 16) | (sbyte(v0.w) << 24);
        ub.y = sbyte(v1.x) | (sbyte(v1.y) << 8) | (sbyte(v1.z) << 16) | (sbyte(v1.w) << 24);
        ub.z = sbyte(v2.x) | (sbyte(v2.y) << 8) | (sbyte(v2.z) << 16) | (sbyte(v2.w) << 24);
        ub.w = sbyte(v3.x) | (sbyte(v3.y) << 8) | (sbyte(v3.z) << 16) | (sbyte(v3.w) << 24);
        ((uint4*)(w8 + (size_t)h * INTER))[t] = ub;

        #pragma unroll
        for (int off = 32; off > 0; off >>= 1) asum += __shfl_down(asum, off);
        __shared__ float red[4];
        if (lane == 0) red[wave] = asum;
        __syncthreads();
        if (t == 0) wscale[h] = (red[0] + red[1] + red[2] + red[3]) * (1.0f / INTER);
    }
}

// expand 4 sign bits -> 4 sign bytes (bit=1 -> 0xFF(-1), bit=0 -> 0x01(+1))
__device__ __forceinline__ unsigned expand4(unsigned bits) {
    unsigned spread = (bits & 1u) | ((bits & 2u) << 7) | ((bits & 4u) << 14) | ((bits & 8u) << 21);
    return 0x01010101u + spread * 0xFEu;
}

// ---------------------------------------------------------------------------
// i8 MFMA GEMM + bias + residual + LayerNorm.
// Block: 32 rows x 1024 cols, 16 waves. Wave w owns n-strip [64w, 64w+64).
// Per 64-k step: 2 A-frags (LDS, fragment-major, conflict-free) x 4 B-frags
// (global, L2-resident) -> 8x mfma_i32_16x16x64_i8.
// A staged per 512-k superstep: bitpacked word -> sign bytes -> LDS, double
// buffered, one barrier per superstep.
// ---------------------------------------------------------------------------
__global__ __launch_bounds__(GTHR, 4)
void gemm_ln_kernel(const u64* __restrict__ abits, const unsigned char* __restrict__ w8,
                    const float* __restrict__ wscale, const float* __restrict__ bias,
                    const float* __restrict__ clipp, const float* __restrict__ input,
                    const float* __restrict__ gamma, const float* __restrict__ beta,
                    float* __restrict__ out) {
    __shared__ uint4 sA[2][GTHR];          // 2 x 16 KB, fragment-major
    __shared__ float red_s[BM][17];
    __shared__ float red_q[BM][17];
    __shared__ float s_mu[BM], s_rs[BM];

    int t = threadIdx.x;
    int lane = t & 63, wave = t >> 6, quad = lane >> 4, l15 = lane & 15;
    int m0 = blockIdx.x * BM;
    int wbase = wave * 64;

    // staging role of this thread: frag block j = t holds
    //   row = mt*16 + (l&15), koff = ks*64 + (l>>4)*16  for j=(ks*2+mt)*64+l
    int ksj  = t >> 7;
    int rem  = t & 127;
    int mtj  = rem >> 6;
    int lj   = rem & 63;
    int rowj = mtj * 16 + (lj & 15);
    int koffj = ksj * 64 + (lj >> 4) * 16;       // 0..496, step 16
    const u64* arow = abits + (size_t)(m0 + rowj) * 64;
    int wordoff = koffj >> 6;                    // which u64 within superstep
    int shift   = ((koffj >> 4) & 3) * 16;       // which 16-bit half

    v4i acc[2][4];
    #pragma unroll
    for (int mt = 0; mt < 2; ++mt)
        #pragma unroll
        for (int nt = 0; nt < 4; ++nt) acc[mt][nt] = (v4i){0, 0, 0, 0};

    // fetch + expand this thread's 16 sign bytes for superstep s
    auto fetch = [&](int s) -> uint4 {
        u64 a = arow[s * 8 + wordoff];
        unsigned hh = (unsigned)(a >> shift) & 0xFFFFu;
        uint4 r;
        r.x = expand4(hh);
        r.y = expand4(hh >> 4);
        r.z = expand4(hh >> 8);
        r.w = expand4(hh >> 12);
        return r;
    };

    sA[0][t] = fetch(0);
    __syncthreads();

    for (int s = 0; s < NSUP; ++s) {
        if (s + 1 < NSUP) sA[(s + 1) & 1][t] = fetch(s + 1);
        const uint4* buf = sA[s & 1];
        int kg = s * KSUP;
        #pragma unroll
        for (int ks = 0; ks < KSUP / 64; ++ks) {
            v4i aF0 = *(const v4i*)&buf[(ks * 2 + 0) * 64 + lane];
            v4i aF1 = *(const v4i*)&buf[(ks * 2 + 1) * 64 + lane];
            #pragma unroll
            for (int nt = 0; nt < 4; ++nt) {
                int n = wbase + nt * 16 + l15;
                v4i bF = *(const v4i*)(w8 + (size_t)n * INTER + kg + ks * 64 + quad * 16);
                acc[0][nt] = __builtin_amdgcn_mfma_i32_16x16x64_i8(aF0, bF, acc[0][nt], 0, 0, 0);
                acc[1][nt] = __builtin_amdgcn_mfma_i32_16x16x64_i8(aF1, bF, acc[1][nt], 0, 0, 0);
            }
        }
        __syncthreads();
    }

    // ---- epilogue: scale + bias + residual, then LayerNorm over n ----
    float clip = clipp[0];
    float cw[4], bi[4], gm[4], bt[4];
    #pragma unroll
    for (int nt = 0; nt < 4; ++nt) {
        int n = wbase + nt * 16 + l15;
        cw[nt] = clip * wscale[n];
        bi[nt] = bias[n];
        gm[nt] = gamma[n];
        bt[nt] = beta[n];
    }

    float vals[2][4][4];   // [mt][nt][reg]
    #pragma unroll
    for (int mt = 0; mt < 2; ++mt)
        #pragma unroll
        for (int reg = 0; reg < 4; ++reg) {
            int m = m0 + mt * 16 + quad * 4 + reg;
            const float* irow = input + (size_t)m * HIDDEN;
            #pragma unroll
            for (int nt = 0; nt < 4; ++nt) {
                int n = wbase + nt * 16 + l15;
                vals[mt][nt][reg] = fmaf((float)acc[mt][nt][reg], cw[nt], bi[nt] + irow[n]);
            }
        }

    // per-row partial sums over this wave's 64 n, then cross-wave via LDS
    #pragma unroll
    for (int mt = 0; mt < 2; ++mt)
        #pragma unroll
        for (int reg = 0; reg < 4; ++reg) {
            float s = vals[mt][0][reg] + vals[mt][1][reg] + vals[mt][2][reg] + vals[mt][3][reg];
            float q = vals[mt][0][reg] * vals[mt][0][reg] + vals[mt][1][reg] * vals[mt][1][reg]
                    + vals[mt][2][reg] * vals[mt][2][reg] + vals[mt][3][reg] * vals[mt][3][reg];
            #pragma unroll
            for (int off = 1; off < 16; off <<= 1) {
                s += __shfl_xor(s, off);
                q += __shfl_xor(q, off);
            }
            if (l15 == 0) {
                int r = mt * 16 + quad * 4 + reg;
                red_s[r][wave] = s;
                red_q[r][wave] = q;
            }
        }
    __syncthreads();
    if (t < BM) {
        float s = 0.f, q = 0.f;
        #pragma unroll
        for (int w = 0; w < 16; ++w) { s += red_s[t][w]; q += red_q[t][w]; }
        float mu  = s * (1.0f / HIDDEN);
        float var = fmaf(-mu, mu, q * (1.0f / HIDDEN));
        s_mu[t] = mu;
        s_rs[t] = rsqrtf(var + 1e-12f);
    }
    __syncthreads();

    #pragma unroll
    for (int mt = 0; mt < 2; ++mt)
        #pragma unroll
        for (int reg = 0; reg < 4; ++reg) {
            int r = mt * 16 + quad * 4 + reg;
            float mu = s_mu[r], rs = s_rs[r];
            float* orow = out + (size_t)(m0 + r) * HIDDEN;
            #pragma unroll
            for (int nt = 0; nt < 4; ++nt) {
                int n = wbase + nt * 16 + l15;
                orow[n] = (vals[mt][nt][reg] - mu) * rs * gm[nt] + bt[nt];
            }
        }
}

// ---------------------------------------------------------------------------
extern "C" void kernel_launch(void* const* d_in, const int* in_sizes, int n_in,
                              void* d_out, int out_size, void* d_ws, size_t ws_size,
                              hipStream_t stream) {
    const float* hs    = (const float*)d_in[0];  // [4,2048,4096]
    const float* inp   = (const float*)d_in[1];  // [4,2048,1024]
    const float* W     = (const float*)d_in[2];  // [1024,4096]
    const float* b     = (const float*)d_in[3];  // [1024]
    const float* clip  = (const float*)d_in[4];  // scalar
    const float* gamma = (const float*)d_in[5];  // [1024]
    const float* beta  = (const float*)d_in[6];  // [1024]
    float* out = (float*)d_out;

    u64*           abits  = (u64*)d_ws;                                   // 4 MB
    unsigned char* w8     = (unsigned char*)d_ws + (size_t)ROWS * 64 * 8; // 4 MB
    float*         wscale = (float*)((unsigned char*)d_ws
                                     + (size_t)ROWS * 64 * 8
                                     + (size_t)HIDDEN * INTER);           // 4 KB

    pack_kernel<<<ROWS + HIDDEN, 256, 0, stream>>>(hs, W, abits, w8, wscale);
    gemm_ln_kernel<<<ROWS / BM, GTHR, 0, stream>>>(abits, w8, wscale, b, clip,
                                                   inp, gamma, beta, out);
}